// Round 1
// baseline (23286.035 us; speedup 1.0000x reference)
//
#include <hip/hip_runtime.h>
#include <cstdint>
#include <cstddef>

#define SS   512
#define BB   64
#define EMBD 768
#define HIDN 512
#define G4   2048
#define NTAG 9

// ---------------------------------------------------------------------------
// Input projection: xp[d][tt][g][b] = sum_e x[b, s(tt,d), e] * w_ih_d[g, e] + bias_d[g]
// Tiled fp32 GEMM, M-tile = 64 (one timestep = all 64 batches), N-tile = 128.
// ---------------------------------------------------------------------------
__global__ __launch_bounds__(256) void proj_kernel(
    const float* __restrict__ x, const float* __restrict__ wih_f,
    const float* __restrict__ wih_b, const float* __restrict__ bias_f,
    const float* __restrict__ bias_b, float* __restrict__ xp,
    int t0, int chunk)
{
  const int d  = blockIdx.z;
  const int tt = blockIdx.y;
  const int g0 = blockIdx.x * 128;
  const int s  = (d == 0) ? (t0 + tt) : (SS - 1 - (t0 + tt));
  const float* __restrict__ wih  = d ? wih_b : wih_f;
  const float* __restrict__ bias = d ? bias_b : bias_f;

  __shared__ float As[16][68];    // [kk][b]   (+pad to dodge write conflicts)
  __shared__ float Bs[16][132];   // [kk][g]

  const int t  = threadIdx.x;
  const int tx = t & 15;          // 16 col-groups of 8
  const int ty = t >> 4;          // 16 row-groups of 4

  float acc[4][8];
#pragma unroll
  for (int i = 0; i < 4; i++)
#pragma unroll
    for (int j = 0; j < 8; j++) acc[i][j] = 0.f;

  const int kqA = t & 3;
  const int bA  = t >> 2;
  const float* xrow = x + ((size_t)bA * SS + s) * EMBD;

  for (int k0 = 0; k0 < EMBD; k0 += 16) {
    float4 av = *reinterpret_cast<const float4*>(xrow + k0 + kqA * 4);
    As[kqA*4+0][bA] = av.x;
    As[kqA*4+1][bA] = av.y;
    As[kqA*4+2][bA] = av.z;
    As[kqA*4+3][bA] = av.w;
#pragma unroll
    for (int r = 0; r < 2; r++) {
      int idx = t + 256 * r;
      int kqB = idx & 3;
      int g   = idx >> 2;         // 0..127
      float4 bv = *reinterpret_cast<const float4*>(wih + (size_t)(g0 + g) * EMBD + k0 + kqB * 4);
      Bs[kqB*4+0][g] = bv.x;
      Bs[kqB*4+1][g] = bv.y;
      Bs[kqB*4+2][g] = bv.z;
      Bs[kqB*4+3][g] = bv.w;
    }
    __syncthreads();
#pragma unroll
    for (int kk = 0; kk < 16; kk++) {
      float4 a4  = *reinterpret_cast<const float4*>(&As[kk][ty * 4]);
      float4 b4a = *reinterpret_cast<const float4*>(&Bs[kk][tx * 8]);
      float4 b4b = *reinterpret_cast<const float4*>(&Bs[kk][tx * 8 + 4]);
      float a[4]  = {a4.x, a4.y, a4.z, a4.w};
      float bv[8] = {b4a.x, b4a.y, b4a.z, b4a.w, b4b.x, b4b.y, b4b.z, b4b.w};
#pragma unroll
      for (int i = 0; i < 4; i++)
#pragma unroll
        for (int j = 0; j < 8; j++) acc[i][j] += a[i] * bv[j];
    }
    __syncthreads();
  }
  float* xpd = xp + (size_t)(d * chunk + tt) * (size_t)G4 * BB;
#pragma unroll
  for (int j = 0; j < 8; j++) {
    int g = g0 + tx * 8 + j;
    float bj = bias[g];
    float4 v;
    v.x = acc[0][j] + bj; v.y = acc[1][j] + bj;
    v.z = acc[2][j] + bj; v.w = acc[3][j] + bj;
    *reinterpret_cast<float4*>(xpd + (size_t)g * BB + ty * 4) = v;
  }
}

// ---------------------------------------------------------------------------
// Recurrence: cooperative kernel, 256 WGs x 256 threads.
// WG = (dir, slice of 4 hidden cols), thread = (batch b, hidden col hc).
// h stored transposed hT[k][b] in hhist slots; c lives in a register.
// w_hh rows read via wave-uniform scalar loads. Custom grid barrier per step.
// ---------------------------------------------------------------------------
struct RecParams {
  const float* xp;
  const float* whh_f;
  const float* whh_b;
  float* hhist;
  float* cT;
  int*   bar;
  int    chunk;
};

__global__ __launch_bounds__(256) void rec_kernel(RecParams p)
{
  const int wg    = blockIdx.x;
  const int d     = wg >> 7;
  const int slice = wg & 127;
  const int t     = threadIdx.x;
  const int b     = t & 63;
  const int hc    = __builtin_amdgcn_readfirstlane(slice * 4 + (t >> 6)); // wave-uniform

  const float* __restrict__ whh = d ? p.whh_b : p.whh_f;
  const float* __restrict__ Wi = whh + (size_t)hc * HIDN;
  const float* __restrict__ Wf = whh + (size_t)(HIDN     + hc) * HIDN;
  const float* __restrict__ Wg = whh + (size_t)(2 * HIDN + hc) * HIDN;
  const float* __restrict__ Wo = whh + (size_t)(3 * HIDN + hc) * HIDN;

  float* hh = p.hhist + (size_t)d * (p.chunk + 1) * (HIDN * BB);
  const float* xpd = p.xp + (size_t)d * p.chunk * ((size_t)G4 * BB);

  float c = p.cT[(size_t)(d * HIDN + hc) * BB + b];
  const int nwg = gridDim.x;
  float hlast = 0.f;

  for (int tt = 0; tt < p.chunk; tt++) {
    const float* __restrict__ hp = hh + (size_t)tt * (HIDN * BB);
    const float* __restrict__ xq = xpd + (size_t)tt * ((size_t)G4 * BB);
    float ai = xq[(size_t)hc * BB + b];
    float af = xq[(size_t)(HIDN     + hc) * BB + b];
    float ag = xq[(size_t)(2 * HIDN + hc) * BB + b];
    float ao = xq[(size_t)(3 * HIDN + hc) * BB + b];
#pragma unroll 8
    for (int k = 0; k < HIDN; k++) {
      float hv = hp[k * BB + b];     // coalesced over b
      ai += hv * Wi[k];              // wave-uniform -> s_load
      af += hv * Wf[k];
      ag += hv * Wg[k];
      ao += hv * Wo[k];
    }
    float ig = 1.f / (1.f + __expf(-ai));
    float fg = 1.f / (1.f + __expf(-af));
    float gg = 1.f - 2.f / (__expf(2.f * ag) + 1.f);   // tanh
    float og = 1.f / (1.f + __expf(-ao));
    c = fg * c + ig * gg;
    float hn = og * (1.f - 2.f / (__expf(2.f * c) + 1.f));
    hh[(size_t)(tt + 1) * (HIDN * BB) + (size_t)hc * BB + b] = hn;
    hlast = hn;

    // grid barrier (monotonic counter, device-scope)
    __syncthreads();
    if (t == 0) {
      __threadfence();                       // release h writes
      atomicAdd(p.bar, 1);
      const int target = nwg * (tt + 1);
      while (__hip_atomic_load(p.bar, __ATOMIC_ACQUIRE, __HIP_MEMORY_SCOPE_AGENT) < target) {
        __builtin_amdgcn_s_sleep(2);
      }
      __threadfence();                       // acquire before reading new h
    }
    __syncthreads();
  }
  // carry state to next chunk launch (safe: past the final barrier)
  hh[(size_t)hc * BB + b] = hlast;
  p.cT[(size_t)(d * HIDN + hc) * BB + b] = c;
}

// ---------------------------------------------------------------------------
// Emissions: emis_d[s][b][tag] = sum_k hT[k][b] * w_out[tag][d*HID + k]
// ---------------------------------------------------------------------------
__global__ __launch_bounds__(640) void emis_kernel(
    const float* __restrict__ hhist, const float* __restrict__ w_out,
    float* __restrict__ emis_f, float* __restrict__ emis_b,
    int t0, int chunk)
{
  const int tt = blockIdx.x;
  const int d  = blockIdx.y;
  const int t  = threadIdx.x;
  if (t >= 576) return;                      // whole-wave exit for wave 9
  const int b   = t & 63;
  const int tag = __builtin_amdgcn_readfirstlane(t >> 6);
  const float* hp   = hhist + ((size_t)d * (chunk + 1) + tt + 1) * (HIDN * BB);
  const float* wrow = w_out + (size_t)tag * (2 * HIDN) + d * HIDN;
  float acc = 0.f;
#pragma unroll 8
  for (int k = 0; k < HIDN; k++) acc += hp[k * BB + b] * wrow[k];
  const int s = (d == 0) ? (t0 + tt) : (SS - 1 - (t0 + tt));
  float* dst = d ? emis_b : emis_f;
  dst[((size_t)s * BB + b) * NTAG + tag] = acc;
}

// ---------------------------------------------------------------------------
// CRF NLL: one wave per batch element. Lanes 0..8 carry alpha; shuffles gather.
// ---------------------------------------------------------------------------
__global__ __launch_bounds__(64) void crf_kernel(
    const float* __restrict__ emis_f, const float* __restrict__ emis_b,
    const float* __restrict__ b_out, const float* __restrict__ start_tr,
    const float* __restrict__ end_tr, const float* __restrict__ trans,
    const int* __restrict__ mask, const int* __restrict__ target,
    float* __restrict__ llh)
{
  const int b    = blockIdx.x;
  const int lane = threadIdx.x;

  auto E = [&](int s, int tg) -> float {
    size_t o = ((size_t)s * BB + b) * NTAG + tg;
    return emis_f[o] + emis_b[o] + b_out[tg];
  };

  // numerator partials + mask sum
  float numpart = 0.f;
  int msum = 0;
  for (int s = lane; s < SS; s += 64) {
    int m = mask[b * SS + s];
    msum += m;
    if (s >= 1 && m > 0) {
      int tp = target[b * SS + s - 1];
      int tc = target[b * SS + s];
      numpart += trans[tp * NTAG + tc] + E(s, tc);
    }
  }
#pragma unroll
  for (int off = 32; off > 0; off >>= 1) {
    numpart += __shfl_down(numpart, off, 64);
    msum    += __shfl_down(msum, off, 64);
  }

  // denominator: forward algorithm, lanes 0..8 hold alpha[t']
  const int tc = lane;
  const bool act = (tc < NTAG);
  float trc[NTAG] = {0.f};
  float alpha = 0.f;
  if (act) {
#pragma unroll
    for (int i = 0; i < NTAG; i++) trc[i] = trans[i * NTAG + tc];
    alpha = start_tr[tc] + E(0, tc);
  }
  for (int s = 1; s < SS; s++) {
    float e = act ? E(s, tc) : 0.f;
    float av[NTAG];
    float mx = -3.0e30f;
#pragma unroll
    for (int i = 0; i < NTAG; i++) {
      av[i] = __shfl(alpha, i, 64) + trc[i];
      mx = fmaxf(mx, av[i]);
    }
    float sum = 0.f;
#pragma unroll
    for (int i = 0; i < NTAG; i++) sum += __expf(av[i] - mx);
    float nxt = mx + __logf(sum) + e;
    if (act && mask[b * SS + s] > 0) alpha = nxt;
  }
  float fv = act ? (alpha + end_tr[tc]) : -3.0e30f;
  float q[NTAG];
  float mx2 = -3.0e30f;
#pragma unroll
  for (int i = 0; i < NTAG; i++) {
    q[i] = __shfl(fv, i, 64);
    mx2 = fmaxf(mx2, q[i]);
  }
  float s2 = 0.f;
#pragma unroll
  for (int i = 0; i < NTAG; i++) s2 += __expf(q[i] - mx2);
  float den = mx2 + __logf(s2);

  if (lane == 0) {
    int last = msum - 1;
    int tg0 = target[b * SS + 0];
    int tgl = target[b * SS + last];
    float num = start_tr[tg0] + E(0, tg0) + numpart + end_tr[tgl];
    llh[b] = num - den;
  }
}

// ---------------------------------------------------------------------------
// Final reduce: out = -(sum llh) / (sum mask)
// ---------------------------------------------------------------------------
__global__ __launch_bounds__(256) void fin_kernel(
    const float* __restrict__ llh, const int* __restrict__ mask,
    float* __restrict__ out)
{
  __shared__ float sf[256];
  __shared__ int   si[256];
  const int t = threadIdx.x;
  float a = (t < BB) ? llh[t] : 0.f;
  int m = 0;
  for (int i = t; i < BB * SS; i += 256) m += mask[i];
  sf[t] = a; si[t] = m;
  __syncthreads();
  for (int o = 128; o > 0; o >>= 1) {
    if (t < o) { sf[t] += sf[t + o]; si[t] += si[t + o]; }
    __syncthreads();
  }
  if (t == 0) out[0] = -(sf[0] / (float)si[0]);
}

// ---------------------------------------------------------------------------
extern "C" void kernel_launch(void* const* d_in, const int* in_sizes, int n_in,
                              void* d_out, int out_size, void* d_ws, size_t ws_size,
                              hipStream_t stream)
{
  const float* x     = (const float*)d_in[0];
  const int*   mask  = (const int*)d_in[1];
  const int*   targ  = (const int*)d_in[2];
  const float* wih_f = (const float*)d_in[3];
  const float* whh_f = (const float*)d_in[4];
  const float* b_f   = (const float*)d_in[5];
  const float* wih_b = (const float*)d_in[6];
  const float* whh_b = (const float*)d_in[7];
  const float* b_b   = (const float*)d_in[8];
  const float* w_out = (const float*)d_in[9];
  const float* b_out = (const float*)d_in[10];
  const float* st    = (const float*)d_in[11];
  const float* et    = (const float*)d_in[12];
  const float* tr    = (const float*)d_in[13];
  float* out = (float*)d_out;

  // chunk = #timesteps of xp + h-history resident at once; pick largest fitting ws
  const size_t fixedf = (size_t)2 * SS * BB * NTAG + 64 + (size_t)2 * HIDN * BB + 64;
  int chunk = 1;
  for (int c = SS; c >= 1; c >>= 1) {
    size_t need = fixedf + (size_t)(c + 1) * 2 * HIDN * BB + (size_t)c * 2 * G4 * BB;
    if (need * sizeof(float) <= ws_size) { chunk = c; break; }
  }

  float* p = (float*)d_ws;
  float* emis_f = p; p += (size_t)SS * BB * NTAG;
  float* emis_b = p; p += (size_t)SS * BB * NTAG;
  float* llh    = p; p += 64;
  float* cT     = p; p += (size_t)2 * HIDN * BB;
  int*   bar    = (int*)p; p += 64;
  float* hhist  = p; p += (size_t)2 * (chunk + 1) * HIDN * BB;
  float* xp     = p;

  hipMemsetAsync(cT, 0, (size_t)2 * HIDN * BB * sizeof(float), stream);
  hipMemsetAsync(hhist, 0, (size_t)HIDN * BB * sizeof(float), stream);
  hipMemsetAsync(hhist + (size_t)(chunk + 1) * HIDN * BB, 0,
                 (size_t)HIDN * BB * sizeof(float), stream);

  const int nch = SS / chunk;
  for (int c = 0; c < nch; c++) {
    const int t0 = c * chunk;
    hipMemsetAsync(bar, 0, sizeof(int), stream);
    proj_kernel<<<dim3(16, chunk, 2), 256, 0, stream>>>(
        x, wih_f, wih_b, b_f, b_b, xp, t0, chunk);
    RecParams rp{xp, whh_f, whh_b, hhist, cT, bar, chunk};
    void* ka[] = {&rp};
    hipLaunchCooperativeKernel(rec_kernel, dim3(256), dim3(256), ka, 0, stream);
    emis_kernel<<<dim3(chunk, 2), 640, 0, stream>>>(
        hhist, w_out, emis_f, emis_b, t0, chunk);
  }
  crf_kernel<<<dim3(64), 64, 0, stream>>>(emis_f, emis_b, b_out, st, et, tr, mask, targ, llh);
  fin_kernel<<<dim3(1), 256, 0, stream>>>(llh, mask, out);
}

// Round 2
// 16471.576 us; speedup vs baseline: 1.4137x; 1.4137x over previous
//
#include <hip/hip_runtime.h>
#include <cstdint>
#include <cstddef>

#define SS   512
#define BB   64
#define EMBD 768
#define HIDN 512
#define G4   2048
#define NTAG 9

typedef __attribute__((ext_vector_type(8))) __bf16 bf16x8;
typedef __attribute__((ext_vector_type(4))) float  f32x4;

// ---------------------------------------------------------------------------
// Input projection: fp32 tiled GEMM. Output written in PACKED column order:
// p = (hc>>2)*16 + (hc&3)*4 + gate, so the rec kernel's MFMA tiles get
// 4 hc x 4 gates in each 16-column slice. xp[d][tt][p][b], b contiguous.
// ---------------------------------------------------------------------------
__global__ __launch_bounds__(256) void proj_kernel(
    const float* __restrict__ x, const float* __restrict__ wih_f,
    const float* __restrict__ wih_b, const float* __restrict__ bias_f,
    const float* __restrict__ bias_b, float* __restrict__ xp,
    int t0, int chunk)
{
  const int d  = blockIdx.z;
  const int tt = blockIdx.y;
  const int g0 = blockIdx.x * 128;
  const int s  = (d == 0) ? (t0 + tt) : (SS - 1 - (t0 + tt));
  const float* __restrict__ wih  = d ? wih_b : wih_f;
  const float* __restrict__ bias = d ? bias_b : bias_f;

  __shared__ float As[16][68];
  __shared__ float Bs[16][132];

  const int t  = threadIdx.x;
  const int tx = t & 15;
  const int ty = t >> 4;

  float acc[4][8];
#pragma unroll
  for (int i = 0; i < 4; i++)
#pragma unroll
    for (int j = 0; j < 8; j++) acc[i][j] = 0.f;

  const int kqA = t & 3;
  const int bA  = t >> 2;
  const float* xrow = x + ((size_t)bA * SS + s) * EMBD;

  for (int k0 = 0; k0 < EMBD; k0 += 16) {
    float4 av = *reinterpret_cast<const float4*>(xrow + k0 + kqA * 4);
    As[kqA*4+0][bA] = av.x;
    As[kqA*4+1][bA] = av.y;
    As[kqA*4+2][bA] = av.z;
    As[kqA*4+3][bA] = av.w;
#pragma unroll
    for (int r = 0; r < 2; r++) {
      int idx = t + 256 * r;
      int kqB = idx & 3;
      int g   = idx >> 2;
      float4 bv = *reinterpret_cast<const float4*>(wih + (size_t)(g0 + g) * EMBD + k0 + kqB * 4);
      Bs[kqB*4+0][g] = bv.x;
      Bs[kqB*4+1][g] = bv.y;
      Bs[kqB*4+2][g] = bv.z;
      Bs[kqB*4+3][g] = bv.w;
    }
    __syncthreads();
#pragma unroll
    for (int kk = 0; kk < 16; kk++) {
      float4 a4  = *reinterpret_cast<const float4*>(&As[kk][ty * 4]);
      float4 b4a = *reinterpret_cast<const float4*>(&Bs[kk][tx * 8]);
      float4 b4b = *reinterpret_cast<const float4*>(&Bs[kk][tx * 8 + 4]);
      float a[4]  = {a4.x, a4.y, a4.z, a4.w};
      float bv[8] = {b4a.x, b4a.y, b4a.z, b4a.w, b4b.x, b4b.y, b4b.z, b4b.w};
#pragma unroll
      for (int i = 0; i < 4; i++)
#pragma unroll
        for (int j = 0; j < 8; j++) acc[i][j] += a[i] * bv[j];
    }
    __syncthreads();
  }
  float* xpd = xp + (size_t)(d * chunk + tt) * (size_t)G4 * BB;
#pragma unroll
  for (int j = 0; j < 8; j++) {
    int g = g0 + tx * 8 + j;
    int gate = g >> 9, hcg = g & 511;
    int pcol = ((hcg >> 2) << 4) + ((hcg & 3) << 2) + gate;   // packed col
    float bj = bias[g];
    float4 v;
    v.x = acc[0][j] + bj; v.y = acc[1][j] + bj;
    v.z = acc[2][j] + bj; v.w = acc[3][j] + bj;
    *reinterpret_cast<float4*>(xpd + (size_t)pcol * BB + ty * 4) = v;
  }
}

// ---------------------------------------------------------------------------
// Recurrence: cooperative, 256 WGs x 256 thr (1 WG/CU). WG = (dir, 16-packed-
// col slice = 4 hc x 4 gates). Wave = 16 batch rows. B-fragments (w_hh bf16)
// preloaded into 64 VGPRs/lane; per step: 16x 16B A-loads (h bf16 [b][k]) +
// 16 MFMA + 4x4 lane transpose + cell update; grid barrier.
// ---------------------------------------------------------------------------
struct RecParams {
  const float* xp;       // [d][chunk][2048 packed][64] fp32
  const float* whh_f;    // [2048][512] fp32
  const float* whh_b;
  __bf16* hh;            // [d][chunk+1][64][512] bf16
  float*  cT;            // [d][512][64] fp32
  int*    bar;
  int     chunk;
};

__global__ __launch_bounds__(256, 1) void rec_kernel(RecParams p)
{
  const int wg   = blockIdx.x;
  const int d    = wg >> 7;
  const int s    = wg & 127;        // packed cols [16s, 16s+16)
  const int t    = threadIdx.x;
  const int wv   = t >> 6;          // batch rows [16wv, 16wv+16)
  const int l    = t & 63;
  const int quad = l >> 4;
  const int col  = l & 15;

  const float* __restrict__ whh = d ? p.whh_b : p.whh_f;

  // --- Preload B fragments: B[k][n] = whh[g_orig(16s+n)][k], k = 32kk+8quad+j
  const int hc   = 4 * s + (col >> 2);
  const int gate = col & 3;
  const int g_orig = gate * HIDN + hc;
  bf16x8 bfrag[16];
  {
    const float* wr = whh + (size_t)g_orig * HIDN + 8 * quad;
#pragma unroll
    for (int kk = 0; kk < 16; kk++) {
      f32x4 w0 = *reinterpret_cast<const f32x4*>(wr + 32 * kk);
      f32x4 w1 = *reinterpret_cast<const f32x4*>(wr + 32 * kk + 4);
      bf16x8 v;
      v[0] = (__bf16)w0[0]; v[1] = (__bf16)w0[1]; v[2] = (__bf16)w0[2]; v[3] = (__bf16)w0[3];
      v[4] = (__bf16)w1[0]; v[5] = (__bf16)w1[1]; v[6] = (__bf16)w1[2]; v[7] = (__bf16)w1[3];
      bfrag[kk] = v;
    }
  }

  const int bA = 16 * wv + col;                 // A-fragment row (batch)
  const int bC = 16 * wv + 4 * quad + gate;     // C-ownership row after transpose
  const size_t slotsz = (size_t)BB * HIDN;      // bf16 elems per step slot
  __bf16* hhd = p.hh + (size_t)d * (p.chunk + 1) * slotsz;
  const float* xpd = p.xp + (size_t)d * p.chunk * ((size_t)G4 * BB);

  float c = p.cT[((size_t)d * HIDN + hc) * BB + bC];
  const int nwg = gridDim.x;
  const int j4  = col & 3;                      // lane index within 4-lane group

  // prefetch first xp tile
  const float* xq0 = xpd + (size_t)(16 * s + col) * BB + 16 * wv + 4 * quad;
  f32x4 xpnext = *reinterpret_cast<const f32x4*>(xq0);

  float hlast = 0.f;
  for (int tt = 0; tt < p.chunk; tt++) {
    // A fragments: h_prev bf16, [b][k] layout
    const __bf16* hp = hhd + (size_t)tt * slotsz + (size_t)bA * HIDN + 8 * quad;
    bf16x8 afrag[16];
#pragma unroll
    for (int kk = 0; kk < 16; kk++)
      afrag[kk] = *reinterpret_cast<const bf16x8*>(hp + 32 * kk);

    f32x4 acc  = xpnext;
    f32x4 acc1 = {0.f, 0.f, 0.f, 0.f};
#pragma unroll
    for (int kk = 0; kk < 16; kk += 2) {
      acc  = __builtin_amdgcn_mfma_f32_16x16x32_bf16(afrag[kk],     bfrag[kk],     acc,  0, 0, 0);
      acc1 = __builtin_amdgcn_mfma_f32_16x16x32_bf16(afrag[kk + 1], bfrag[kk + 1], acc1, 0, 0, 0);
    }
    float v0 = acc[0] + acc1[0];
    float v1 = acc[1] + acc1[1];
    float v2 = acc[2] + acc1[2];
    float v3 = acc[3] + acc1[3];

    // 4x4 transpose across (reg, lane-in-group): rounds k=1,2
    {
      float t0 = __shfl_xor(v1, 1); float t1 = __shfl_xor(v0, 1);
      float t2 = __shfl_xor(v3, 1); float t3 = __shfl_xor(v2, 1);
      if (j4 & 1) { v0 = t0; v2 = t2; } else { v1 = t1; v3 = t3; }
      float u0 = __shfl_xor(v2, 2); float u1 = __shfl_xor(v3, 2);
      float u2 = __shfl_xor(v0, 2); float u3 = __shfl_xor(v1, 2);
      if (j4 & 2) { v0 = u0; v1 = u1; } else { v2 = u2; v3 = u3; }
    }
    // now v0..v3 = pre-activations i,f,g,o for (bC, hc)
    float ig = 1.f / (1.f + __expf(-v0));
    float fg = 1.f / (1.f + __expf(-v1));
    float gg = 1.f - 2.f / (__expf(2.f * v2) + 1.f);
    float og = 1.f / (1.f + __expf(-v3));
    c = fg * c + ig * gg;
    float hn = og * (1.f - 2.f / (__expf(2.f * c) + 1.f));
    hhd[(size_t)(tt + 1) * slotsz + (size_t)bC * HIDN + hc] = (__bf16)hn;
    hlast = hn;

    // prefetch next xp tile (overlaps barrier wait)
    if (tt + 1 < p.chunk) {
      const float* xq = xpd + (size_t)(tt + 1) * ((size_t)G4 * BB)
                      + (size_t)(16 * s + col) * BB + 16 * wv + 4 * quad;
      xpnext = *reinterpret_cast<const f32x4*>(xq);
    }

    // grid barrier
    __syncthreads();
    if (t == 0) {
      __threadfence();
      atomicAdd(p.bar, 1);
      const int target = nwg * (tt + 1);
      while (__hip_atomic_load(p.bar, __ATOMIC_ACQUIRE, __HIP_MEMORY_SCOPE_AGENT) < target) {
        __builtin_amdgcn_s_sleep(1);
      }
      __threadfence();
    }
    __syncthreads();
  }
  // carry state to next chunk launch
  hhd[(size_t)bC * HIDN + hc] = (__bf16)hlast;
  p.cT[((size_t)d * HIDN + hc) * BB + bC] = c;
}

// ---------------------------------------------------------------------------
// Emissions from bf16 h history: emis_d[s][b][tag] = h[b][:] . w_out[tag][dHID:]
// thread = (b, tag-group); groups cover tags {g, g+4, g+8?}.
// ---------------------------------------------------------------------------
__global__ __launch_bounds__(256) void emis_kernel(
    const __bf16* __restrict__ hh, const float* __restrict__ w_out,
    float* __restrict__ emis_f, float* __restrict__ emis_b,
    int t0, int chunk)
{
  const int tt = blockIdx.x;
  const int d  = blockIdx.y;
  const int t  = threadIdx.x;
  const int b  = t & 63;
  const int grp = t >> 6;

  const __bf16* hp = hh + ((size_t)d * (chunk + 1) + tt + 1) * ((size_t)BB * HIDN)
                   + (size_t)b * HIDN;
  const float* w0 = w_out + (size_t)grp * (2 * HIDN) + d * HIDN;
  const float* w1 = w_out + (size_t)(grp + 4) * (2 * HIDN) + d * HIDN;
  const float* w2 = w_out + (size_t)8 * (2 * HIDN) + d * HIDN;   // tag 8 (grp 0 only)

  float a0 = 0.f, a1 = 0.f, a2 = 0.f;
  for (int k = 0; k < HIDN; k += 8) {
    bf16x8 hv8 = *reinterpret_cast<const bf16x8*>(hp + k);
#pragma unroll
    for (int j = 0; j < 8; j++) {
      float hv = (float)hv8[j];
      a0 += hv * w0[k + j];
      a1 += hv * w1[k + j];
      a2 += hv * w2[k + j];
    }
  }
  const int sidx = (d == 0) ? (t0 + tt) : (SS - 1 - (t0 + tt));
  float* dst = d ? emis_b : emis_f;
  dst[((size_t)sidx * BB + b) * NTAG + grp]     = a0;
  dst[((size_t)sidx * BB + b) * NTAG + grp + 4] = a1;
  if (grp == 0) dst[((size_t)sidx * BB + b) * NTAG + 8] = a2;
}

// ---------------------------------------------------------------------------
// CRF NLL: one wave per batch element (unchanged from R1).
// ---------------------------------------------------------------------------
__global__ __launch_bounds__(64) void crf_kernel(
    const float* __restrict__ emis_f, const float* __restrict__ emis_b,
    const float* __restrict__ b_out, const float* __restrict__ start_tr,
    const float* __restrict__ end_tr, const float* __restrict__ trans,
    const int* __restrict__ mask, const int* __restrict__ target,
    float* __restrict__ llh)
{
  const int b    = blockIdx.x;
  const int lane = threadIdx.x;

  auto E = [&](int s, int tg) -> float {
    size_t o = ((size_t)s * BB + b) * NTAG + tg;
    return emis_f[o] + emis_b[o] + b_out[tg];
  };

  float numpart = 0.f;
  int msum = 0;
  for (int s = lane; s < SS; s += 64) {
    int m = mask[b * SS + s];
    msum += m;
    if (s >= 1 && m > 0) {
      int tp = target[b * SS + s - 1];
      int tc = target[b * SS + s];
      numpart += trans[tp * NTAG + tc] + E(s, tc);
    }
  }
#pragma unroll
  for (int off = 32; off > 0; off >>= 1) {
    numpart += __shfl_down(numpart, off, 64);
    msum    += __shfl_down(msum, off, 64);
  }

  const int tc = lane;
  const bool act = (tc < NTAG);
  float trc[NTAG] = {0.f};
  float alpha = 0.f;
  if (act) {
#pragma unroll
    for (int i = 0; i < NTAG; i++) trc[i] = trans[i * NTAG + tc];
    alpha = start_tr[tc] + E(0, tc);
  }
  for (int s = 1; s < SS; s++) {
    float e = act ? E(s, tc) : 0.f;
    float av[NTAG];
    float mx = -3.0e30f;
#pragma unroll
    for (int i = 0; i < NTAG; i++) {
      av[i] = __shfl(alpha, i, 64) + trc[i];
      mx = fmaxf(mx, av[i]);
    }
    float sum = 0.f;
#pragma unroll
    for (int i = 0; i < NTAG; i++) sum += __expf(av[i] - mx);
    float nxt = mx + __logf(sum) + e;
    if (act && mask[b * SS + s] > 0) alpha = nxt;
  }
  float fv = act ? (alpha + end_tr[tc]) : -3.0e30f;
  float q[NTAG];
  float mx2 = -3.0e30f;
#pragma unroll
  for (int i = 0; i < NTAG; i++) {
    q[i] = __shfl(fv, i, 64);
    mx2 = fmaxf(mx2, q[i]);
  }
  float s2 = 0.f;
#pragma unroll
  for (int i = 0; i < NTAG; i++) s2 += __expf(q[i] - mx2);
  float den = mx2 + __logf(s2);

  if (lane == 0) {
    int last = msum - 1;
    int tg0 = target[b * SS + 0];
    int tgl = target[b * SS + last];
    float num = start_tr[tg0] + E(0, tg0) + numpart + end_tr[tgl];
    llh[b] = num - den;
  }
}

__global__ __launch_bounds__(256) void fin_kernel(
    const float* __restrict__ llh, const int* __restrict__ mask,
    float* __restrict__ out)
{
  __shared__ float sf[256];
  __shared__ int   si[256];
  const int t = threadIdx.x;
  float a = (t < BB) ? llh[t] : 0.f;
  int m = 0;
  for (int i = t; i < BB * SS; i += 256) m += mask[i];
  sf[t] = a; si[t] = m;
  __syncthreads();
  for (int o = 128; o > 0; o >>= 1) {
    if (t < o) { sf[t] += sf[t + o]; si[t] += si[t + o]; }
    __syncthreads();
  }
  if (t == 0) out[0] = -(sf[0] / (float)si[0]);
}

// ---------------------------------------------------------------------------
extern "C" void kernel_launch(void* const* d_in, const int* in_sizes, int n_in,
                              void* d_out, int out_size, void* d_ws, size_t ws_size,
                              hipStream_t stream)
{
  const float* x     = (const float*)d_in[0];
  const int*   mask  = (const int*)d_in[1];
  const int*   targ  = (const int*)d_in[2];
  const float* wih_f = (const float*)d_in[3];
  const float* whh_f = (const float*)d_in[4];
  const float* b_f   = (const float*)d_in[5];
  const float* wih_b = (const float*)d_in[6];
  const float* whh_b = (const float*)d_in[7];
  const float* b_b   = (const float*)d_in[8];
  const float* w_out = (const float*)d_in[9];
  const float* b_out = (const float*)d_in[10];
  const float* st    = (const float*)d_in[11];
  const float* et    = (const float*)d_in[12];
  const float* tr    = (const float*)d_in[13];
  float* out = (float*)d_out;

  // pick largest power-of-2 chunk that fits: xp fp32 + h-history bf16
  const size_t fixed_b = ((size_t)2 * SS * BB * NTAG + 64 + (size_t)2 * HIDN * BB) * 4
                       + 64 * sizeof(int);
  int chunk = 1;
  for (int c = SS; c >= 1; c >>= 1) {
    size_t need = fixed_b + (size_t)c * 2 * G4 * BB * 4
                + (size_t)2 * (c + 1) * BB * HIDN * 2;
    if (need <= ws_size) { chunk = c; break; }
  }

  float* fp = (float*)d_ws;
  float* emis_f = fp; fp += (size_t)SS * BB * NTAG;
  float* emis_b = fp; fp += (size_t)SS * BB * NTAG;
  float* llh    = fp; fp += 64;
  float* cT     = fp; fp += (size_t)2 * HIDN * BB;
  int*   bar    = (int*)fp; fp += 64;
  float* xp     = fp; fp += (size_t)chunk * 2 * G4 * BB;
  __bf16* hh    = (__bf16*)fp;

  const size_t slotsz = (size_t)BB * HIDN;
  hipMemsetAsync(cT, 0, (size_t)2 * HIDN * BB * sizeof(float), stream);
  hipMemsetAsync(hh, 0, slotsz * sizeof(__bf16), stream);
  hipMemsetAsync(hh + (size_t)(chunk + 1) * slotsz, 0, slotsz * sizeof(__bf16), stream);

  const int nch = SS / chunk;
  for (int c = 0; c < nch; c++) {
    const int t0 = c * chunk;
    hipMemsetAsync(bar, 0, sizeof(int), stream);
    proj_kernel<<<dim3(16, chunk, 2), 256, 0, stream>>>(
        x, wih_f, wih_b, b_f, b_b, xp, t0, chunk);
    RecParams rp{xp, whh_f, whh_b, hh, cT, bar, chunk};
    void* ka[] = {&rp};
    hipLaunchCooperativeKernel(rec_kernel, dim3(256), dim3(256), ka, 0, stream);
    emis_kernel<<<dim3(chunk, 2), 256, 0, stream>>>(
        hh, w_out, emis_f, emis_b, t0, chunk);
  }
  crf_kernel<<<dim3(64), 64, 0, stream>>>(emis_f, emis_b, b_out, st, et, tr, mask, targ, llh);
  fin_kernel<<<dim3(1), 256, 0, stream>>>(llh, mask, out);
}

// Round 3
// 6362.526 us; speedup vs baseline: 3.6599x; 2.5888x over previous
//
#include <hip/hip_runtime.h>
#include <cstdint>
#include <cstddef>

#define SS   512
#define BB   64
#define EMBD 768
#define HIDN 512
#define G4   2048
#define NTAG 9

typedef __attribute__((ext_vector_type(8))) __bf16 bf16x8;
typedef __attribute__((ext_vector_type(4))) float  f32x4;
typedef unsigned long long u64;

union HCast { f32x4 f; bf16x8 h; };

// 16 pipelined 16B loads that bypass L1+L2 (sc0 sc1) -> coherent view of h.
__device__ inline void load_h16(const void* base, f32x4* f) {
  asm volatile(
    "global_load_dwordx4 %0, %16, off sc0 sc1\n\t"
    "global_load_dwordx4 %1, %16, off offset:64 sc0 sc1\n\t"
    "global_load_dwordx4 %2, %16, off offset:128 sc0 sc1\n\t"
    "global_load_dwordx4 %3, %16, off offset:192 sc0 sc1\n\t"
    "global_load_dwordx4 %4, %16, off offset:256 sc0 sc1\n\t"
    "global_load_dwordx4 %5, %16, off offset:320 sc0 sc1\n\t"
    "global_load_dwordx4 %6, %16, off offset:384 sc0 sc1\n\t"
    "global_load_dwordx4 %7, %16, off offset:448 sc0 sc1\n\t"
    "global_load_dwordx4 %8, %16, off offset:512 sc0 sc1\n\t"
    "global_load_dwordx4 %9, %16, off offset:576 sc0 sc1\n\t"
    "global_load_dwordx4 %10, %16, off offset:640 sc0 sc1\n\t"
    "global_load_dwordx4 %11, %16, off offset:704 sc0 sc1\n\t"
    "global_load_dwordx4 %12, %16, off offset:768 sc0 sc1\n\t"
    "global_load_dwordx4 %13, %16, off offset:832 sc0 sc1\n\t"
    "global_load_dwordx4 %14, %16, off offset:896 sc0 sc1\n\t"
    "global_load_dwordx4 %15, %16, off offset:960 sc0 sc1\n\t"
    "s_waitcnt vmcnt(0)"
    : "=&v"(f[0]), "=&v"(f[1]), "=&v"(f[2]), "=&v"(f[3]),
      "=&v"(f[4]), "=&v"(f[5]), "=&v"(f[6]), "=&v"(f[7]),
      "=&v"(f[8]), "=&v"(f[9]), "=&v"(f[10]), "=&v"(f[11]),
      "=&v"(f[12]), "=&v"(f[13]), "=&v"(f[14]), "=&v"(f[15])
    : "v"(base)
    : "memory");
}

__device__ inline void store_h8_bypass(void* p, u64 v) {
  asm volatile("global_store_dwordx2 %0, %1, off sc0 sc1" :: "v"(p), "v"(v) : "memory");
}

__device__ inline int load_i32_bypass(const int* p) {
  int v;
  asm volatile("global_load_dword %0, %1, off sc0 sc1\n\ts_waitcnt vmcnt(0)"
               : "=v"(v) : "v"(p) : "memory");
  return v;
}

// ---------------------------------------------------------------------------
// Input projection (fp32 tiled GEMM). Packed column order chosen so the rec
// kernel's tile j covers hc === j (mod 4):
//   pcol = (hc>>4)*64 + (hc&3)*16 + ((hc>>2)&3)*4 + gate
// xp[d][tt][pcol][b], b contiguous.
// ---------------------------------------------------------------------------
__global__ __launch_bounds__(256) void proj_kernel(
    const float* __restrict__ x, const float* __restrict__ wih_f,
    const float* __restrict__ wih_b, const float* __restrict__ bias_f,
    const float* __restrict__ bias_b, float* __restrict__ xp,
    int t0, int chunk)
{
  const int d  = blockIdx.z;
  const int tt = blockIdx.y;
  const int g0 = blockIdx.x * 128;
  const int s  = (d == 0) ? (t0 + tt) : (SS - 1 - (t0 + tt));
  const float* __restrict__ wih  = d ? wih_b : wih_f;
  const float* __restrict__ bias = d ? bias_b : bias_f;

  __shared__ float As[16][68];
  __shared__ float Bs[16][132];

  const int t  = threadIdx.x;
  const int tx = t & 15;
  const int ty = t >> 4;

  float acc[4][8];
#pragma unroll
  for (int i = 0; i < 4; i++)
#pragma unroll
    for (int j = 0; j < 8; j++) acc[i][j] = 0.f;

  const int kqA = t & 3;
  const int bA  = t >> 2;
  const float* xrow = x + ((size_t)bA * SS + s) * EMBD;

  for (int k0 = 0; k0 < EMBD; k0 += 16) {
    float4 av = *reinterpret_cast<const float4*>(xrow + k0 + kqA * 4);
    As[kqA*4+0][bA] = av.x;
    As[kqA*4+1][bA] = av.y;
    As[kqA*4+2][bA] = av.z;
    As[kqA*4+3][bA] = av.w;
#pragma unroll
    for (int r = 0; r < 2; r++) {
      int idx = t + 256 * r;
      int kqB = idx & 3;
      int g   = idx >> 2;
      float4 bv = *reinterpret_cast<const float4*>(wih + (size_t)(g0 + g) * EMBD + k0 + kqB * 4);
      Bs[kqB*4+0][g] = bv.x;
      Bs[kqB*4+1][g] = bv.y;
      Bs[kqB*4+2][g] = bv.z;
      Bs[kqB*4+3][g] = bv.w;
    }
    __syncthreads();
#pragma unroll
    for (int kk = 0; kk < 16; kk++) {
      float4 a4  = *reinterpret_cast<const float4*>(&As[kk][ty * 4]);
      float4 b4a = *reinterpret_cast<const float4*>(&Bs[kk][tx * 8]);
      float4 b4b = *reinterpret_cast<const float4*>(&Bs[kk][tx * 8 + 4]);
      float a[4]  = {a4.x, a4.y, a4.z, a4.w};
      float bv[8] = {b4a.x, b4a.y, b4a.z, b4a.w, b4b.x, b4b.y, b4b.z, b4b.w};
#pragma unroll
      for (int i = 0; i < 4; i++)
#pragma unroll
        for (int j = 0; j < 8; j++) acc[i][j] += a[i] * bv[j];
    }
    __syncthreads();
  }
  float* xpd = xp + (size_t)(d * chunk + tt) * (size_t)G4 * BB;
#pragma unroll
  for (int j = 0; j < 8; j++) {
    int g = g0 + tx * 8 + j;
    int gate = g >> 9, hcg = g & 511;
    int pcol = ((hcg >> 4) << 6) + ((hcg & 3) << 4) + (((hcg >> 2) & 3) << 2) + gate;
    float bj = bias[g];
    float4 v;
    v.x = acc[0][j] + bj; v.y = acc[1][j] + bj;
    v.z = acc[2][j] + bj; v.w = acc[3][j] + bj;
    *reinterpret_cast<float4*>(xpd + (size_t)pcol * BB + ty * 4) = v;
  }
}

// ---------------------------------------------------------------------------
// Recurrence: cooperative, 64 WGs x 256 thr. WG = (d, sl) owns 64 packed cols
// = hc in [16sl,16sl+16) x 4 gates, as 4 MFMA col-tiles (tile j: hc===j mod 4).
// w_hh bf16 B-fragments resident in 256 VGPRs. Per step: 16 bypass 16B h-loads,
// 64 MFMA, 4x (4x4 lane transpose + cell update), one 8B write-through h-store,
// fence-free relaxed barrier over 64 WGs.
// ---------------------------------------------------------------------------
struct RecParams {
  const float* xp;       // [d][chunk][2048 packed][64] fp32
  const float* whh_f;    // [2048][512] fp32
  const float* whh_b;
  __bf16* hh;            // [d][chunk+1][64][512] bf16
  float*  cT;            // [d][512][64] fp32
  int*    bar;
  int     chunk;
};

__global__ __launch_bounds__(256, 1) void rec_kernel(RecParams p)
{
  const int wg   = blockIdx.x;
  const int d    = wg >> 5;
  const int sl   = wg & 31;         // hc block [16sl, 16sl+16)
  const int t    = threadIdx.x;
  const int wv   = t >> 6;          // batch rows [16wv, 16wv+16)
  const int l    = t & 63;
  const int quad = l >> 4;
  const int col  = l & 15;
  const int hcl  = col >> 2;
  const int gate = col & 3;
  const int j4   = col & 3;

  const float* __restrict__ whh = d ? p.whh_b : p.whh_f;

  // --- Preload B fragments: tile j, lane supplies B[k][col], k = 32kk+8quad+i
  //     column col of tile j -> hc = 16sl + 4*hcl + j, g_orig = gate*512 + hc
  bf16x8 bfrag[4][16];
#pragma unroll
  for (int j = 0; j < 4; j++) {
    const int hcb = 16 * sl + 4 * hcl + j;
    const float* wr = whh + (size_t)(gate * HIDN + hcb) * HIDN + 8 * quad;
#pragma unroll
    for (int kk = 0; kk < 16; kk++) {
      f32x4 w0 = *reinterpret_cast<const f32x4*>(wr + 32 * kk);
      f32x4 w1 = *reinterpret_cast<const f32x4*>(wr + 32 * kk + 4);
      bf16x8 v;
      v[0] = (__bf16)w0[0]; v[1] = (__bf16)w0[1]; v[2] = (__bf16)w0[2]; v[3] = (__bf16)w0[3];
      v[4] = (__bf16)w1[0]; v[5] = (__bf16)w1[1]; v[6] = (__bf16)w1[2]; v[7] = (__bf16)w1[3];
      bfrag[j][kk] = v;
    }
  }

  const int bA = 16 * wv + col;                 // A-fragment row (batch)
  const int bC = 16 * wv + 4 * quad + gate;     // post-transpose batch row
  const int hcs = 16 * sl + 4 * hcl;            // this thread's 4 contig hc base
  const size_t slotsz = (size_t)BB * HIDN;
  __bf16* hhd = p.hh + (size_t)d * (p.chunk + 1) * slotsz;
  const float* xpd = p.xp + (size_t)d * p.chunk * ((size_t)G4 * BB);

  float c[4];
#pragma unroll
  for (int j = 0; j < 4; j++)
    c[j] = p.cT[((size_t)d * HIDN + hcs + j) * BB + bC];

  const int nwg = gridDim.x;

  // prefetch first xp tiles
  f32x4 xpn[4];
#pragma unroll
  for (int j = 0; j < 4; j++)
    xpn[j] = *reinterpret_cast<const f32x4*>(
        xpd + (size_t)(64 * sl + 16 * j + col) * BB + 16 * wv + 4 * quad);

  u64 hword = 0;
  for (int tt = 0; tt < p.chunk; tt++) {
    // A fragments: h_prev bf16, [b][k] layout, bypass loads (coherent view)
    const char* hbase = (const char*)hhd + (size_t)tt * slotsz * 2
                      + (size_t)bA * (HIDN * 2) + quad * 16;
    f32x4 araw[16];
    load_h16(hbase, araw);
    bf16x8 afrag[16];
#pragma unroll
    for (int kk = 0; kk < 16; kk++) { HCast hc_; hc_.f = araw[kk]; afrag[kk] = hc_.h; }

    // 4 tiles x 16 MFMA, 8 independent chains
    f32x4 acc[4][2];
#pragma unroll
    for (int j = 0; j < 4; j++) {
      acc[j][0] = xpn[j];
      acc[j][1] = f32x4{0.f, 0.f, 0.f, 0.f};
    }
#pragma unroll
    for (int kk = 0; kk < 16; kk += 2) {
#pragma unroll
      for (int j = 0; j < 4; j++) {
        acc[j][0] = __builtin_amdgcn_mfma_f32_16x16x32_bf16(afrag[kk],     bfrag[j][kk],     acc[j][0], 0, 0, 0);
        acc[j][1] = __builtin_amdgcn_mfma_f32_16x16x32_bf16(afrag[kk + 1], bfrag[j][kk + 1], acc[j][1], 0, 0, 0);
      }
    }

    // per tile: transpose + cell update
    hword = 0;
#pragma unroll
    for (int j = 0; j < 4; j++) {
      float v0 = acc[j][0][0] + acc[j][1][0];
      float v1 = acc[j][0][1] + acc[j][1][1];
      float v2 = acc[j][0][2] + acc[j][1][2];
      float v3 = acc[j][0][3] + acc[j][1][3];
      {
        float t0 = __shfl_xor(v1, 1); float t1 = __shfl_xor(v0, 1);
        float t2 = __shfl_xor(v3, 1); float t3 = __shfl_xor(v2, 1);
        if (j4 & 1) { v0 = t0; v2 = t2; } else { v1 = t1; v3 = t3; }
        float u0 = __shfl_xor(v2, 2); float u1 = __shfl_xor(v3, 2);
        float u2 = __shfl_xor(v0, 2); float u3 = __shfl_xor(v1, 2);
        if (j4 & 2) { v0 = u0; v1 = u1; } else { v2 = u2; v3 = u3; }
      }
      float ig = 1.f / (1.f + __expf(-v0));
      float fg = 1.f / (1.f + __expf(-v1));
      float gg = 1.f - 2.f / (__expf(2.f * v2) + 1.f);
      float og = 1.f / (1.f + __expf(-v3));
      c[j] = fg * c[j] + ig * gg;
      float hn = og * (1.f - 2.f / (__expf(2.f * c[j]) + 1.f));
      union { __bf16 b; unsigned short u; } cv; cv.b = (__bf16)hn;
      hword |= (u64)cv.u << (16 * j);
    }
    // one 8B write-through store: h[bC][hcs..hcs+3]
    store_h8_bypass((char*)hhd + (size_t)(tt + 1) * slotsz * 2
                    + (size_t)bC * (HIDN * 2) + (size_t)hcs * 2, hword);

    // prefetch next xp tiles (cached loads; overlap barrier wait)
    if (tt + 1 < p.chunk) {
#pragma unroll
      for (int j = 0; j < 4; j++)
        xpn[j] = *reinterpret_cast<const f32x4*>(
            xpd + (size_t)(tt + 1) * ((size_t)G4 * BB)
            + (size_t)(64 * sl + 16 * j + col) * BB + 16 * wv + 4 * quad);
    }

    // fence-free grid barrier (relaxed atomics; data already write-through)
    __builtin_amdgcn_s_waitcnt(0);
    __syncthreads();
    if (t == 0) {
      atomicAdd(p.bar, 1);
      const int target = nwg * (tt + 1);
      while (load_i32_bypass(p.bar) < target) __builtin_amdgcn_s_sleep(1);
    }
    __syncthreads();
    __atomic_signal_fence(__ATOMIC_SEQ_CST);
  }

  // carry state to next chunk launch
  store_h8_bypass((char*)hhd + (size_t)bC * (HIDN * 2) + (size_t)hcs * 2, hword);
#pragma unroll
  for (int j = 0; j < 4; j++)
    p.cT[((size_t)d * HIDN + hcs + j) * BB + bC] = c[j];
}

// ---------------------------------------------------------------------------
// Emissions from bf16 h history.
// ---------------------------------------------------------------------------
__global__ __launch_bounds__(256) void emis_kernel(
    const __bf16* __restrict__ hh, const float* __restrict__ w_out,
    float* __restrict__ emis_f, float* __restrict__ emis_b,
    int t0, int chunk)
{
  const int tt = blockIdx.x;
  const int d  = blockIdx.y;
  const int t  = threadIdx.x;
  const int b  = t & 63;
  const int grp = t >> 6;

  const __bf16* hp = hh + ((size_t)d * (chunk + 1) + tt + 1) * ((size_t)BB * HIDN)
                   + (size_t)b * HIDN;
  const float* w0 = w_out + (size_t)grp * (2 * HIDN) + d * HIDN;
  const float* w1 = w_out + (size_t)(grp + 4) * (2 * HIDN) + d * HIDN;
  const float* w2 = w_out + (size_t)8 * (2 * HIDN) + d * HIDN;

  float a0 = 0.f, a1 = 0.f, a2 = 0.f;
  for (int k = 0; k < HIDN; k += 8) {
    bf16x8 hv8 = *reinterpret_cast<const bf16x8*>(hp + k);
#pragma unroll
    for (int j = 0; j < 8; j++) {
      float hv = (float)hv8[j];
      a0 += hv * w0[k + j];
      a1 += hv * w1[k + j];
      a2 += hv * w2[k + j];
    }
  }
  const int sidx = (d == 0) ? (t0 + tt) : (SS - 1 - (t0 + tt));
  float* dst = d ? emis_b : emis_f;
  dst[((size_t)sidx * BB + b) * NTAG + grp]     = a0;
  dst[((size_t)sidx * BB + b) * NTAG + grp + 4] = a1;
  if (grp == 0) dst[((size_t)sidx * BB + b) * NTAG + 8] = a2;
}

// ---------------------------------------------------------------------------
// CRF NLL: one wave per batch element.
// ---------------------------------------------------------------------------
__global__ __launch_bounds__(64) void crf_kernel(
    const float* __restrict__ emis_f, const float* __restrict__ emis_b,
    const float* __restrict__ b_out, const float* __restrict__ start_tr,
    const float* __restrict__ end_tr, const float* __restrict__ trans,
    const int* __restrict__ mask, const int* __restrict__ target,
    float* __restrict__ llh)
{
  const int b    = blockIdx.x;
  const int lane = threadIdx.x;

  auto E = [&](int s, int tg) -> float {
    size_t o = ((size_t)s * BB + b) * NTAG + tg;
    return emis_f[o] + emis_b[o] + b_out[tg];
  };

  float numpart = 0.f;
  int msum = 0;
  for (int s = lane; s < SS; s += 64) {
    int m = mask[b * SS + s];
    msum += m;
    if (s >= 1 && m > 0) {
      int tp = target[b * SS + s - 1];
      int tc = target[b * SS + s];
      numpart += trans[tp * NTAG + tc] + E(s, tc);
    }
  }
#pragma unroll
  for (int off = 32; off > 0; off >>= 1) {
    numpart += __shfl_down(numpart, off, 64);
    msum    += __shfl_down(msum, off, 64);
  }

  const int tc = lane;
  const bool act = (tc < NTAG);
  float trc[NTAG] = {0.f};
  float alpha = 0.f;
  if (act) {
#pragma unroll
    for (int i = 0; i < NTAG; i++) trc[i] = trans[i * NTAG + tc];
    alpha = start_tr[tc] + E(0, tc);
  }
  for (int s = 1; s < SS; s++) {
    float e = act ? E(s, tc) : 0.f;
    float av[NTAG];
    float mx = -3.0e30f;
#pragma unroll
    for (int i = 0; i < NTAG; i++) {
      av[i] = __shfl(alpha, i, 64) + trc[i];
      mx = fmaxf(mx, av[i]);
    }
    float sum = 0.f;
#pragma unroll
    for (int i = 0; i < NTAG; i++) sum += __expf(av[i] - mx);
    float nxt = mx + __logf(sum) + e;
    if (act && mask[b * SS + s] > 0) alpha = nxt;
  }
  float fv = act ? (alpha + end_tr[tc]) : -3.0e30f;
  float q[NTAG];
  float mx2 = -3.0e30f;
#pragma unroll
  for (int i = 0; i < NTAG; i++) {
    q[i] = __shfl(fv, i, 64);
    mx2 = fmaxf(mx2, q[i]);
  }
  float s2 = 0.f;
#pragma unroll
  for (int i = 0; i < NTAG; i++) s2 += __expf(q[i] - mx2);
  float den = mx2 + __logf(s2);

  if (lane == 0) {
    int last = msum - 1;
    int tg0 = target[b * SS + 0];
    int tgl = target[b * SS + last];
    float num = start_tr[tg0] + E(0, tg0) + numpart + end_tr[tgl];
    llh[b] = num - den;
  }
}

__global__ __launch_bounds__(256) void fin_kernel(
    const float* __restrict__ llh, const int* __restrict__ mask,
    float* __restrict__ out)
{
  __shared__ float sf[256];
  __shared__ int   si[256];
  const int t = threadIdx.x;
  float a = (t < BB) ? llh[t] : 0.f;
  int m = 0;
  for (int i = t; i < BB * SS; i += 256) m += mask[i];
  sf[t] = a; si[t] = m;
  __syncthreads();
  for (int o = 128; o > 0; o >>= 1) {
    if (t < o) { sf[t] += sf[t + o]; si[t] += si[t + o]; }
    __syncthreads();
  }
  if (t == 0) out[0] = -(sf[0] / (float)si[0]);
}

// ---------------------------------------------------------------------------
extern "C" void kernel_launch(void* const* d_in, const int* in_sizes, int n_in,
                              void* d_out, int out_size, void* d_ws, size_t ws_size,
                              hipStream_t stream)
{
  const float* x     = (const float*)d_in[0];
  const int*   mask  = (const int*)d_in[1];
  const int*   targ  = (const int*)d_in[2];
  const float* wih_f = (const float*)d_in[3];
  const float* whh_f = (const float*)d_in[4];
  const float* b_f   = (const float*)d_in[5];
  const float* wih_b = (const float*)d_in[6];
  const float* whh_b = (const float*)d_in[7];
  const float* b_b   = (const float*)d_in[8];
  const float* w_out = (const float*)d_in[9];
  const float* b_out = (const float*)d_in[10];
  const float* st    = (const float*)d_in[11];
  const float* et    = (const float*)d_in[12];
  const float* tr    = (const float*)d_in[13];
  float* out = (float*)d_out;

  const size_t fixed_b = ((size_t)2 * SS * BB * NTAG + 64 + (size_t)2 * HIDN * BB) * 4
                       + 64 * sizeof(int);
  int chunk = 1;
  for (int c = SS; c >= 1; c >>= 1) {
    size_t need = fixed_b + (size_t)c * 2 * G4 * BB * 4
                + (size_t)2 * (c + 1) * BB * HIDN * 2;
    if (need <= ws_size) { chunk = c; break; }
  }

  float* fp = (float*)d_ws;
  float* emis_f = fp; fp += (size_t)SS * BB * NTAG;
  float* emis_b = fp; fp += (size_t)SS * BB * NTAG;
  float* llh    = fp; fp += 64;
  float* cT     = fp; fp += (size_t)2 * HIDN * BB;
  int*   bar    = (int*)fp; fp += 64;
  float* xp     = fp; fp += (size_t)chunk * 2 * G4 * BB;
  __bf16* hh    = (__bf16*)fp;

  const size_t slotsz = (size_t)BB * HIDN;
  hipMemsetAsync(cT, 0, (size_t)2 * HIDN * BB * sizeof(float), stream);
  hipMemsetAsync(hh, 0, slotsz * sizeof(__bf16), stream);
  hipMemsetAsync(hh + (size_t)(chunk + 1) * slotsz, 0, slotsz * sizeof(__bf16), stream);

  const int nch = SS / chunk;
  for (int c = 0; c < nch; c++) {
    const int t0 = c * chunk;
    hipMemsetAsync(bar, 0, sizeof(int), stream);
    proj_kernel<<<dim3(16, chunk, 2), 256, 0, stream>>>(
        x, wih_f, wih_b, b_f, b_b, xp, t0, chunk);
    RecParams rp{xp, whh_f, whh_b, hh, cT, bar, chunk};
    void* ka[] = {&rp};
    hipLaunchCooperativeKernel(rec_kernel, dim3(64), dim3(256), ka, 0, stream);
    emis_kernel<<<dim3(chunk, 2), 256, 0, stream>>>(
        hh, w_out, emis_f, emis_b, t0, chunk);
  }
  crf_kernel<<<dim3(64), 64, 0, stream>>>(emis_f, emis_b, b_out, st, et, tr, mask, targ, llh);
  fin_kernel<<<dim3(1), 256, 0, stream>>>(llh, mask, out);
}

// Round 5
// 5000.743 us; speedup vs baseline: 4.6565x; 1.2723x over previous
//
#include <hip/hip_runtime.h>
#include <cstdint>
#include <cstddef>

#define SS   512
#define BB   64
#define EMBD 768
#define HIDN 512
#define G4   2048
#define NTAG 9

typedef __attribute__((ext_vector_type(8))) __bf16 bf16x8;
typedef __attribute__((ext_vector_type(4))) float  f32x4;
typedef unsigned long long u64;

union HCast { f32x4 f; bf16x8 h; };

// ---- device-scope (coherence-point) bypass ops: sc0 sc1 --------------------
__device__ inline void load_h16_bypass(const void* base, f32x4* f) {
  asm volatile(
    "global_load_dwordx4 %0, %16, off sc0 sc1\n\t"
    "global_load_dwordx4 %1, %16, off offset:64 sc0 sc1\n\t"
    "global_load_dwordx4 %2, %16, off offset:128 sc0 sc1\n\t"
    "global_load_dwordx4 %3, %16, off offset:192 sc0 sc1\n\t"
    "global_load_dwordx4 %4, %16, off offset:256 sc0 sc1\n\t"
    "global_load_dwordx4 %5, %16, off offset:320 sc0 sc1\n\t"
    "global_load_dwordx4 %6, %16, off offset:384 sc0 sc1\n\t"
    "global_load_dwordx4 %7, %16, off offset:448 sc0 sc1\n\t"
    "global_load_dwordx4 %8, %16, off offset:512 sc0 sc1\n\t"
    "global_load_dwordx4 %9, %16, off offset:576 sc0 sc1\n\t"
    "global_load_dwordx4 %10, %16, off offset:640 sc0 sc1\n\t"
    "global_load_dwordx4 %11, %16, off offset:704 sc0 sc1\n\t"
    "global_load_dwordx4 %12, %16, off offset:768 sc0 sc1\n\t"
    "global_load_dwordx4 %13, %16, off offset:832 sc0 sc1\n\t"
    "global_load_dwordx4 %14, %16, off offset:896 sc0 sc1\n\t"
    "global_load_dwordx4 %15, %16, off offset:960 sc0 sc1\n\t"
    "s_waitcnt vmcnt(0)"
    : "=&v"(f[0]), "=&v"(f[1]), "=&v"(f[2]), "=&v"(f[3]),
      "=&v"(f[4]), "=&v"(f[5]), "=&v"(f[6]), "=&v"(f[7]),
      "=&v"(f[8]), "=&v"(f[9]), "=&v"(f[10]), "=&v"(f[11]),
      "=&v"(f[12]), "=&v"(f[13]), "=&v"(f[14]), "=&v"(f[15])
    : "v"(base)
    : "memory");
}
__device__ inline void store_h8_bypass(void* p, u64 v) {
  asm volatile("global_store_dwordx2 %0, %1, off sc0 sc1" :: "v"(p), "v"(v) : "memory");
}
__device__ inline void store_i32_bypass(int* p, int v) {
  asm volatile("global_store_dword %0, %1, off sc0 sc1" :: "v"(p), "v"(v) : "memory");
}
__device__ inline int load_i32_bypass(const int* p) {
  int v;
  asm volatile("global_load_dword %0, %1, off sc0 sc1\n\ts_waitcnt vmcnt(0)"
               : "=v"(v) : "v"(p) : "memory");
  return v;
}

// ---------------------------------------------------------------------------
// fp32 -> bf16 converter (grid-stride free, one elem-group per thread)
// ---------------------------------------------------------------------------
__global__ __launch_bounds__(256) void cvt_kernel(
    const float* __restrict__ src, __bf16* __restrict__ dst, int n8)
{
  int i = blockIdx.x * 256 + threadIdx.x;
  if (i >= n8) return;
  f32x4 a = *reinterpret_cast<const f32x4*>(src + 8 * (size_t)i);
  f32x4 b = *reinterpret_cast<const f32x4*>(src + 8 * (size_t)i + 4);
  bf16x8 o;
  o[0]=(__bf16)a[0]; o[1]=(__bf16)a[1]; o[2]=(__bf16)a[2]; o[3]=(__bf16)a[3];
  o[4]=(__bf16)b[0]; o[5]=(__bf16)b[1]; o[6]=(__bf16)b[2]; o[7]=(__bf16)b[3];
  *reinterpret_cast<bf16x8*>(dst + 8 * (size_t)i) = o;
}

// ---------------------------------------------------------------------------
// Input projection, bf16 MFMA. Same fragment pattern as rec_kernel:
// A lane m=col: x_bf16[b=16wv+col][s][k], B lane n=col: w_ih[g(p)][k].
// C (col = packed col p within tile, rows = batch) stored directly to
// xp[d][tt][p][b]. pcol <-> (hc,gate): gate=p&3, hc=16*(p>>6)+4*((p>>2)&3)+((p>>4)&3).
// ---------------------------------------------------------------------------
__global__ __launch_bounds__(256, 2) void proj_kernel(
    const __bf16* __restrict__ xb, const __bf16* __restrict__ wfb,
    const __bf16* __restrict__ wbb, const float* __restrict__ bias_f,
    const float* __restrict__ bias_b, float* __restrict__ xp,
    int t0, int chunk)
{
  const int nb = blockIdx.x;                    // 16 blocks of 128 pcols
  const int tt = blockIdx.y;
  const int d  = blockIdx.z;
  const int s  = d ? (SS - 1 - (t0 + tt)) : (t0 + tt);
  const __bf16* __restrict__ wih = d ? wbb : wfb;
  const float*  __restrict__ bias = d ? bias_b : bias_f;

  const int t = threadIdx.x, wv = t >> 6, l = t & 63;
  const int quad = l >> 4, col = l & 15;

  const __bf16* brow[8];
  float bj[8];
  const int pbase = 128 * nb;
#pragma unroll
  for (int j = 0; j < 8; j++) {
    int p    = pbase + 16 * j + col;
    int gate = p & 3;
    int hc   = 16 * (p >> 6) + 4 * ((p >> 2) & 3) + ((p >> 4) & 3);
    int g    = gate * HIDN + hc;
    brow[j]  = wih + (size_t)g * EMBD + 8 * quad;
    bj[j]    = bias[g];
  }
  const __bf16* arow = xb + ((size_t)(16 * wv + col) * SS + s) * EMBD + 8 * quad;

  f32x4 acc[8];
#pragma unroll
  for (int j = 0; j < 8; j++) acc[j] = f32x4{0.f, 0.f, 0.f, 0.f};

  for (int kk = 0; kk < 24; kk++) {
    bf16x8 a = *reinterpret_cast<const bf16x8*>(arow + 32 * kk);
#pragma unroll
    for (int j = 0; j < 8; j++) {
      bf16x8 b = *reinterpret_cast<const bf16x8*>(brow[j] + 32 * kk);
      acc[j] = __builtin_amdgcn_mfma_f32_16x16x32_bf16(a, b, acc[j], 0, 0, 0);
    }
  }
  float* xpd = xp + (size_t)(d * chunk + tt) * (size_t)G4 * BB + 16 * wv + 4 * quad;
#pragma unroll
  for (int j = 0; j < 8; j++) {
    int p = pbase + 16 * j + col;
    f32x4 v = acc[j];
    v[0] += bj[j]; v[1] += bj[j]; v[2] += bj[j]; v[3] += bj[j];
    *reinterpret_cast<f32x4*>(xpd + (size_t)p * BB) = v;
  }
}

// ---------------------------------------------------------------------------
// Recurrence: cooperative, 64 WGs x 256 thr (R3 structure). Barrier uses
// per-WG progress flags (plain write-through stores, no RMW) polled by wave 0
// with one pipelined 32-slot read + ballot.
// ---------------------------------------------------------------------------
struct RecCtl {
  int prog[2][64];     // per-dir 32 slots used (+pad), 4B stride for vector poll
  int pad[128];
};

struct RecParams {
  const float* xp;       // [d][chunk][2048 packed][64] fp32
  const float* whh_f;    // [2048][512] fp32
  const float* whh_b;
  __bf16* hh;            // [d][chunk+1][64][512] bf16
  float*  cT;            // [d][512][64] fp32
  RecCtl* ctl;
  int     chunk;
};

__global__ __launch_bounds__(256, 1) void rec_kernel(RecParams p)
{
  const int wg   = blockIdx.x;
  const int d    = wg >> 5;
  const int sl   = wg & 31;
  const int t    = threadIdx.x;
  const int wv   = t >> 6;
  const int l    = t & 63;
  const int quad = l >> 4;
  const int col  = l & 15;
  const int hcl  = col >> 2;
  const int gate = col & 3;
  const int j4   = col & 3;

  const float* __restrict__ whh = d ? p.whh_b : p.whh_f;

  bf16x8 bfrag[4][16];
#pragma unroll
  for (int j = 0; j < 4; j++) {
    const int hcb = 16 * sl + 4 * hcl + j;
    const float* wr = whh + (size_t)(gate * HIDN + hcb) * HIDN + 8 * quad;
#pragma unroll
    for (int kk = 0; kk < 16; kk++) {
      f32x4 w0 = *reinterpret_cast<const f32x4*>(wr + 32 * kk);
      f32x4 w1 = *reinterpret_cast<const f32x4*>(wr + 32 * kk + 4);
      bf16x8 v;
      v[0] = (__bf16)w0[0]; v[1] = (__bf16)w0[1]; v[2] = (__bf16)w0[2]; v[3] = (__bf16)w0[3];
      v[4] = (__bf16)w1[0]; v[5] = (__bf16)w1[1]; v[6] = (__bf16)w1[2]; v[7] = (__bf16)w1[3];
      bfrag[j][kk] = v;
    }
  }

  const int bA = 16 * wv + col;
  const int bC = 16 * wv + 4 * quad + gate;
  const int hcs = 16 * sl + 4 * hcl;
  const size_t slotsz = (size_t)BB * HIDN;
  __bf16* hhd = p.hh + (size_t)d * (p.chunk + 1) * slotsz;
  const float* xpd = p.xp + (size_t)d * p.chunk * ((size_t)G4 * BB);

  float c[4];
#pragma unroll
  for (int j = 0; j < 4; j++)
    c[j] = p.cT[((size_t)d * HIDN + hcs + j) * BB + bC];

  f32x4 xpn[4];
#pragma unroll
  for (int j = 0; j < 4; j++)
    xpn[j] = *reinterpret_cast<const f32x4*>(
        xpd + (size_t)(64 * sl + 16 * j + col) * BB + 16 * wv + 4 * quad);

  int* prog = &p.ctl->prog[d][0];
  const int* myslot = prog + (l & 31);

  u64 hword = 0;
  for (int tt = 0; tt < p.chunk; tt++) {
    const char* hbase = (const char*)hhd + (size_t)tt * slotsz * 2
                      + (size_t)bA * (HIDN * 2) + quad * 16;
    f32x4 araw[16];
    load_h16_bypass(hbase, araw);
    bf16x8 afrag[16];
#pragma unroll
    for (int kk = 0; kk < 16; kk++) { HCast hc_; hc_.f = araw[kk]; afrag[kk] = hc_.h; }

    f32x4 acc[4][2];
#pragma unroll
    for (int j = 0; j < 4; j++) {
      acc[j][0] = xpn[j];
      acc[j][1] = f32x4{0.f, 0.f, 0.f, 0.f};
    }
#pragma unroll
    for (int kk = 0; kk < 16; kk += 2) {
#pragma unroll
      for (int j = 0; j < 4; j++) {
        acc[j][0] = __builtin_amdgcn_mfma_f32_16x16x32_bf16(afrag[kk],     bfrag[j][kk],     acc[j][0], 0, 0, 0);
        acc[j][1] = __builtin_amdgcn_mfma_f32_16x16x32_bf16(afrag[kk + 1], bfrag[j][kk + 1], acc[j][1], 0, 0, 0);
      }
    }

    hword = 0;
#pragma unroll
    for (int j = 0; j < 4; j++) {
      float v0 = acc[j][0][0] + acc[j][1][0];
      float v1 = acc[j][0][1] + acc[j][1][1];
      float v2 = acc[j][0][2] + acc[j][1][2];
      float v3 = acc[j][0][3] + acc[j][1][3];
      {
        float t0 = __shfl_xor(v1, 1); float t1 = __shfl_xor(v0, 1);
        float t2 = __shfl_xor(v3, 1); float t3 = __shfl_xor(v2, 1);
        if (j4 & 1) { v0 = t0; v2 = t2; } else { v1 = t1; v3 = t3; }
        float u0 = __shfl_xor(v2, 2); float u1 = __shfl_xor(v3, 2);
        float u2 = __shfl_xor(v0, 2); float u3 = __shfl_xor(v1, 2);
        if (j4 & 2) { v0 = u0; v1 = u1; } else { v2 = u2; v3 = u3; }
      }
      float ig = 1.f / (1.f + __expf(-v0));
      float fg = 1.f / (1.f + __expf(-v1));
      float gg = 1.f - 2.f / (__expf(2.f * v2) + 1.f);
      float og = 1.f / (1.f + __expf(-v3));
      c[j] = fg * c[j] + ig * gg;
      float hn = og * (1.f - 2.f / (__expf(2.f * c[j]) + 1.f));
      union { __bf16 b; unsigned short u; } cv; cv.b = (__bf16)hn;
      hword |= (u64)cv.u << (16 * j);
    }
    store_h8_bypass((char*)hhd + (size_t)(tt + 1) * slotsz * 2
                    + (size_t)bC * (HIDN * 2) + (size_t)hcs * 2, hword);

    if (tt + 1 < p.chunk) {
#pragma unroll
      for (int j = 0; j < 4; j++)
        xpn[j] = *reinterpret_cast<const f32x4*>(
            xpd + (size_t)(tt + 1) * ((size_t)G4 * BB)
            + (size_t)(64 * sl + 16 * j + col) * BB + 16 * wv + 4 * quad);
    }

    // --- flag barrier: h stores drained -> publish progress -> vector poll
    __builtin_amdgcn_s_waitcnt(0);
    __syncthreads();
    if (t == 0) store_i32_bypass(prog + sl, tt + 1);
    if (wv == 0) {
      const int tgt = tt + 1;
      while (true) {
        int v = load_i32_bypass(myslot);
        if (__ballot(v >= tgt) == ~0ull) break;
        __builtin_amdgcn_s_sleep(1);
      }
    }
    __syncthreads();
    __atomic_signal_fence(__ATOMIC_SEQ_CST);
  }

  store_h8_bypass((char*)hhd + (size_t)bC * (HIDN * 2) + (size_t)hcs * 2, hword);
#pragma unroll
  for (int j = 0; j < 4; j++)
    p.cT[((size_t)d * HIDN + hcs + j) * BB + bC] = c[j];
}

// ---------------------------------------------------------------------------
__global__ __launch_bounds__(256) void emis_kernel(
    const __bf16* __restrict__ hh, const float* __restrict__ w_out,
    float* __restrict__ emis_f, float* __restrict__ emis_b,
    int t0, int chunk)
{
  const int tt = blockIdx.x;
  const int d  = blockIdx.y;
  const int t  = threadIdx.x;
  const int b  = t & 63;
  const int grp = t >> 6;

  const __bf16* hp = hh + ((size_t)d * (chunk + 1) + tt + 1) * ((size_t)BB * HIDN)
                   + (size_t)b * HIDN;
  const float* w0 = w_out + (size_t)grp * (2 * HIDN) + d * HIDN;
  const float* w1 = w_out + (size_t)(grp + 4) * (2 * HIDN) + d * HIDN;
  const float* w2 = w_out + (size_t)8 * (2 * HIDN) + d * HIDN;

  float a0 = 0.f, a1 = 0.f, a2 = 0.f;
  for (int k = 0; k < HIDN; k += 8) {
    bf16x8 hv8 = *reinterpret_cast<const bf16x8*>(hp + k);
#pragma unroll
    for (int j = 0; j < 8; j++) {
      float hv = (float)hv8[j];
      a0 += hv * w0[k + j];
      a1 += hv * w1[k + j];
      a2 += hv * w2[k + j];
    }
  }
  const int sidx = (d == 0) ? (t0 + tt) : (SS - 1 - (t0 + tt));
  float* dst = d ? emis_b : emis_f;
  dst[((size_t)sidx * BB + b) * NTAG + grp]     = a0;
  dst[((size_t)sidx * BB + b) * NTAG + grp + 4] = a1;
  if (grp == 0) dst[((size_t)sidx * BB + b) * NTAG + 8] = a2;
}

// ---------------------------------------------------------------------------
__global__ __launch_bounds__(64) void crf_kernel(
    const float* __restrict__ emis_f, const float* __restrict__ emis_b,
    const float* __restrict__ b_out, const float* __restrict__ start_tr,
    const float* __restrict__ end_tr, const float* __restrict__ trans,
    const int* __restrict__ mask, const int* __restrict__ target,
    float* __restrict__ llh)
{
  const int b    = blockIdx.x;
  const int lane = threadIdx.x;

  auto E = [&](int s, int tg) -> float {
    size_t o = ((size_t)s * BB + b) * NTAG + tg;
    return emis_f[o] + emis_b[o] + b_out[tg];
  };

  float numpart = 0.f;
  int msum = 0;
  for (int s = lane; s < SS; s += 64) {
    int m = mask[b * SS + s];
    msum += m;
    if (s >= 1 && m > 0) {
      int tp = target[b * SS + s - 1];
      int tc = target[b * SS + s];
      numpart += trans[tp * NTAG + tc] + E(s, tc);
    }
  }
#pragma unroll
  for (int off = 32; off > 0; off >>= 1) {
    numpart += __shfl_down(numpart, off, 64);
    msum    += __shfl_down(msum, off, 64);
  }

  const int tc = lane;
  const bool act = (tc < NTAG);
  float trc[NTAG] = {0.f};
  float alpha = 0.f;
  if (act) {
#pragma unroll
    for (int i = 0; i < NTAG; i++) trc[i] = trans[i * NTAG + tc];
    alpha = start_tr[tc] + E(0, tc);
  }
  for (int s = 1; s < SS; s++) {
    float e = act ? E(s, tc) : 0.f;
    float av[NTAG];
    float mx = -3.0e30f;
#pragma unroll
    for (int i = 0; i < NTAG; i++) {
      av[i] = __shfl(alpha, i, 64) + trc[i];
      mx = fmaxf(mx, av[i]);
    }
    float sum = 0.f;
#pragma unroll
    for (int i = 0; i < NTAG; i++) sum += __expf(av[i] - mx);
    float nxt = mx + __logf(sum) + e;
    if (act && mask[b * SS + s] > 0) alpha = nxt;
  }
  float fv = act ? (alpha + end_tr[tc]) : -3.0e30f;
  float q[NTAG];
  float mx2 = -3.0e30f;
#pragma unroll
  for (int i = 0; i < NTAG; i++) {
    q[i] = __shfl(fv, i, 64);
    mx2 = fmaxf(mx2, q[i]);
  }
  float s2 = 0.f;
#pragma unroll
  for (int i = 0; i < NTAG; i++) s2 += __expf(q[i] - mx2);
  float den = mx2 + __logf(s2);

  if (lane == 0) {
    int last = msum - 1;
    int tg0 = target[b * SS + 0];
    int tgl = target[b * SS + last];
    float num = start_tr[tg0] + E(0, tg0) + numpart + end_tr[tgl];
    llh[b] = num - den;
  }
}

__global__ __launch_bounds__(256) void fin_kernel(
    const float* __restrict__ llh, const int* __restrict__ mask,
    float* __restrict__ out)
{
  __shared__ float sf[256];
  __shared__ int   si[256];
  const int t = threadIdx.x;
  float a = (t < BB) ? llh[t] : 0.f;
  int m = 0;
  for (int i = t; i < BB * SS; i += 256) m += mask[i];
  sf[t] = a; si[t] = m;
  __syncthreads();
  for (int o = 128; o > 0; o >>= 1) {
    if (t < o) { sf[t] += sf[t + o]; si[t] += si[t + o]; }
    __syncthreads();
  }
  if (t == 0) out[0] = -(sf[0] / (float)si[0]);
}

// ---------------------------------------------------------------------------
extern "C" void kernel_launch(void* const* d_in, const int* in_sizes, int n_in,
                              void* d_out, int out_size, void* d_ws, size_t ws_size,
                              hipStream_t stream)
{
  const float* x     = (const float*)d_in[0];
  const int*   mask  = (const int*)d_in[1];
  const int*   targ  = (const int*)d_in[2];
  const float* wih_f = (const float*)d_in[3];
  const float* whh_f = (const float*)d_in[4];
  const float* b_f   = (const float*)d_in[5];
  const float* wih_b = (const float*)d_in[6];
  const float* whh_b = (const float*)d_in[7];
  const float* b_b   = (const float*)d_in[8];
  const float* w_out = (const float*)d_in[9];
  const float* b_out = (const float*)d_in[10];
  const float* st    = (const float*)d_in[11];
  const float* et    = (const float*)d_in[12];
  const float* tr    = (const float*)d_in[13];
  float* out = (float*)d_out;

  const size_t nxb   = (size_t)BB * SS * EMBD;       // x bf16 elements
  const size_t nwb   = (size_t)G4 * EMBD;            // w_ih bf16 elements (per dir)
  const size_t ctl_i = sizeof(RecCtl) / 4;
  // fixed floats: emis(2) + llh + cT + ctl + xb16/2 + 2*wih16/2
  const size_t fixed_f = (size_t)2 * SS * BB * NTAG + 64 + (size_t)2 * HIDN * BB
                       + ctl_i + nxb / 2 + nwb;
  int chunk = 1;
  for (int c = SS; c >= 1; c >>= 1) {
    size_t need = fixed_f * 4 + (size_t)c * 2 * G4 * BB * 4
                + (size_t)2 * (c + 1) * BB * HIDN * 2;
    if (need <= ws_size) { chunk = c; break; }
  }

  float* fp = (float*)d_ws;
  float* emis_f = fp; fp += (size_t)SS * BB * NTAG;
  float* emis_b = fp; fp += (size_t)SS * BB * NTAG;
  float* llh    = fp; fp += 64;
  float* cT     = fp; fp += (size_t)2 * HIDN * BB;
  RecCtl* ctl   = (RecCtl*)fp; fp += ctl_i;
  __bf16* xb16  = (__bf16*)fp; fp += nxb / 2;
  __bf16* wfb16 = (__bf16*)fp; fp += nwb / 2;
  __bf16* wbb16 = (__bf16*)fp; fp += nwb / 2;
  float* xp     = fp; fp += (size_t)chunk * 2 * G4 * BB;
  __bf16* hh    = (__bf16*)fp;

  // one-time converts (idempotent per launch; inputs restored each replay)
  {
    int n8 = (int)(nxb / 8);
    cvt_kernel<<<dim3((n8 + 255) / 256), 256, 0, stream>>>(x, xb16, n8);
    int w8 = (int)(nwb / 8);
    cvt_kernel<<<dim3((w8 + 255) / 256), 256, 0, stream>>>(wih_f, wfb16, w8);
    cvt_kernel<<<dim3((w8 + 255) / 256), 256, 0, stream>>>(wih_b, wbb16, w8);
  }

  const size_t slotsz = (size_t)BB * HIDN;
  hipMemsetAsync(cT, 0, (size_t)2 * HIDN * BB * sizeof(float), stream);
  hipMemsetAsync(hh, 0, slotsz * sizeof(__bf16), stream);
  hipMemsetAsync(hh + (size_t)(chunk + 1) * slotsz, 0, slotsz * sizeof(__bf16), stream);

  const int nch = SS / chunk;
  for (int c = 0; c < nch; c++) {
    const int t0 = c * chunk;
    hipMemsetAsync(ctl, 0, sizeof(RecCtl), stream);
    proj_kernel<<<dim3(16, chunk, 2), 256, 0, stream>>>(
        xb16, wfb16, wbb16, b_f, b_b, xp, t0, chunk);
    RecParams rp{xp, whh_f, whh_b, hh, cT, ctl, chunk};
    void* ka[] = {&rp};
    hipLaunchCooperativeKernel(rec_kernel, dim3(64), dim3(256), ka, 0, stream);
    emis_kernel<<<dim3(chunk, 2), 256, 0, stream>>>(
        hh, w_out, emis_f, emis_b, t0, chunk);
  }
  crf_kernel<<<dim3(64), 64, 0, stream>>>(emis_f, emis_b, b_out, st, et, tr, mask, targ, llh);
  fin_kernel<<<dim3(1), 256, 0, stream>>>(llh, mask, out);
}